// Round 2
// baseline (667.415 us; speedup 1.0000x reference)
//
#include <hip/hip_runtime.h>
#include <math.h>

// Problem constants (match reference).
#define BB 512
#define KK 32
#define DD 768
#define NEG_INF (-1e30f)
#define NCAND (BB * KK)   // 16384 candidates

// Kernel A: one wave per candidate (b,k). 4096 blocks x 256 thr = 16384 waves.
// Lane reads 3 x float4 (48 B) of the gathered weight row (coalesced 16 B/lane),
// dot with reps[b] (L2-cached, reused 32x), 64-lane butterfly reduce,
// lane 0 writes logit to ws. Also zero-inits out[0] for kernel B's atomics.
__global__ __launch_bounds__(256) void cbert_logits_kernel(
    const float* __restrict__ reps,      // [B, D]
    const float* __restrict__ weight,    // [N, D]
    const float* __restrict__ bias,      // [N]
    const int*   __restrict__ sense_ids, // [B*K]
    float* __restrict__ logits_ws,       // [B*K]
    float* __restrict__ out)             // [1 + B]
{
    if (blockIdx.x == 0 && threadIdx.x == 0) out[0] = 0.0f;

    const int c    = blockIdx.x * 4 + (threadIdx.x >> 6);  // candidate 0..16383
    const int lane = threadIdx.x & 63;
    const int b    = c >> 5;

    const int id = sense_ids[c];
    float logit = NEG_INF;
    if (id >= 0) {
        const float4* wrow = reinterpret_cast<const float4*>(weight + (size_t)id * DD);
        const float4* rrow = reinterpret_cast<const float4*>(reps   + (size_t)b  * DD);
        float acc = 0.0f;
        #pragma unroll
        for (int j = 0; j < 3; ++j) {
            const float4 w4 = wrow[j * 64 + lane];
            const float4 r4 = rrow[j * 64 + lane];
            acc += w4.x * r4.x + w4.y * r4.y + w4.z * r4.z + w4.w * r4.w;
        }
        #pragma unroll
        for (int off = 32; off >= 1; off >>= 1)
            acc += __shfl_xor(acc, off, 64);
        logit = acc + bias[id];
    }
    if (lane == 0) logits_ws[c] = logit;
}

// Kernel B: one wave per sample. Lanes 0..31 hold the K logits; butterfly
// max/argmax (first-occurrence tie-break = smallest index) + sum-exp.
// Lane 0 writes correct flag and atomically accumulates nll/B into out[0].
__global__ __launch_bounds__(512) void cbert_ce_kernel(
    const float* __restrict__ logits_ws, // [B*K]
    const int*   __restrict__ target_ids,// [B]
    float* __restrict__ out)             // [1 + B]
{
    const int wave = threadIdx.x >> 6;
    const int lane = threadIdx.x & 63;
    const int b    = blockIdx.x * 8 + wave;

    float myv;
    int   myi;
    if (lane < KK) {
        myv = logits_ws[b * KK + lane];
        myi = lane;
    } else {
        myv = -INFINITY;
        myi = 64;
    }

    // max + argmax with smallest-index tie-break.
    float mv = myv;
    int   mi = myi;
    #pragma unroll
    for (int off = 1; off < 64; off <<= 1) {
        const float ov = __shfl_xor(mv, off, 64);
        const int   oi = __shfl_xor(mi, off, 64);
        if (ov > mv || (ov == mv && oi < mi)) { mv = ov; mi = oi; }
    }

    // sum of exp(logit - max); padded lanes contribute exp(-inf) = 0.
    float e = expf(myv - mv);
    #pragma unroll
    for (int off = 1; off < 64; off <<= 1)
        e += __shfl_xor(e, off, 64);

    if (lane == 0) {
        const int   tgt = target_ids[b];
        const float lt  = logits_ws[b * KK + tgt];
        const float nll = -(lt - mv - logf(e));
        atomicAdd(&out[0], nll * (1.0f / (float)BB));
        out[1 + b] = (mi == tgt) ? 1.0f : 0.0f;
    }
}

extern "C" void kernel_launch(void* const* d_in, const int* in_sizes, int n_in,
                              void* d_out, int out_size, void* d_ws, size_t ws_size,
                              hipStream_t stream) {
    const float* reps       = (const float*)d_in[0];
    const float* weight     = (const float*)d_in[1];
    const float* bias       = (const float*)d_in[2];
    const int*   sense_ids  = (const int*)d_in[3];
    const int*   target_ids = (const int*)d_in[4];
    float* out       = (float*)d_out;
    float* logits_ws = (float*)d_ws;  // 16384 floats

    cbert_logits_kernel<<<NCAND / 4, 256, 0, stream>>>(
        reps, weight, bias, sense_ids, logits_ws, out);
    cbert_ce_kernel<<<BB / 8, 512, 0, stream>>>(logits_ws, target_ids, out);
}